// Round 2
// baseline (601.413 us; speedup 1.0000x reference)
//
#include <hip/hip_runtime.h>

// Problem constants (from reference)
#define BATCH   2048
#define SEQ     160     // input sequence stride
#define LOUT    128     // END - START
#define D_MODEL 256
#define NBINS   16
#define LN_EPS  1e-5f

__device__ __forceinline__ void fma4(float4& h, float s, const float4& w) {
    h.x = fmaf(s, w.x, h.x);
    h.y = fmaf(s, w.y, h.y);
    h.z = fmaf(s, w.z, h.z);
    h.w = fmaf(s, w.w, h.w);
}

__device__ __forceinline__ float compf(const float4& v, int q) {
    return q == 0 ? v.x : q == 1 ? v.y : q == 2 ? v.z : v.w;
}
__device__ __forceinline__ int compi(const int4& v, int q) {
    return q == 0 ? v.x : q == 1 ? v.y : q == 2 ? v.z : v.w;
}

// One wave per chunk of 4 consecutive rows (same b; 128 % 4 == 0).
// 4 independent dependency chains per wave -> latency hiding via ILP.
// Block = 256 threads = 4 waves; grid-stride over 65536 chunks.
__global__ __launch_bounds__(256, 4)
void action_embedding_kernel(
    const int*   __restrict__ token_ids,      // (B, SEQ)
    const int*   __restrict__ action_actors,  // (B, SEQ)
    const int*   __restrict__ action_streets, // (B, SEQ)
    const float* __restrict__ legal_masks,    // (B, SEQ, NBINS)
    const float* __restrict__ actor_w,        // (2, D)
    const float* __restrict__ street_w,       // (4, D)
    const float* __restrict__ pos_w,          // (LOUT, D)
    const float* __restrict__ mlp_w,          // (NBINS, D)
    const float* __restrict__ mlp_b,          // (D,)
    const float* __restrict__ ln_g,           // (D,)
    const float* __restrict__ ln_b,           // (D,)
    float*       __restrict__ out)            // (B, LOUT, D)
{
    const int lane = threadIdx.x & 63;
    const int wave = threadIdx.x >> 6;   // 0..3
    const int d0   = lane << 2;          // 0..252

    const float4 b4  = *reinterpret_cast<const float4*>(&mlp_b[d0]);
    const float4 g4  = *reinterpret_cast<const float4*>(&ln_g[d0]);
    const float4 lb4 = *reinterpret_cast<const float4*>(&ln_b[d0]);

    const int nchunks = (BATCH * LOUT) / 4;      // 65536
    const int wid     = blockIdx.x * 4 + wave;
    const int nw      = gridDim.x * 4;

    for (int c = wid; c < nchunks; c += nw) {
        const int b  = c >> 5;             // (c*4) / 128
        const int l0 = (c << 2) & 127;     // (c*4) % 128
        int off = b * SEQ + l0;
        off = __builtin_amdgcn_readfirstlane(off);   // wave-uniform -> SMEM-eligible

        // Per-row metadata for 4 consecutive rows (16B aligned: off % 4 == 0)
        const int4 tokv = *reinterpret_cast<const int4*>(&token_ids[off]);
        const int4 actv = *reinterpret_cast<const int4*>(&action_actors[off]);
        const int4 strv = *reinterpret_cast<const int4*>(&action_streets[off]);

        // Masks: 4 rows x 16 floats (wave-uniform address)
        const float4* mp = reinterpret_cast<const float4*>(&legal_masks[(size_t)off * NBINS]);
        float4 m[4][4];
#pragma unroll
        for (int r = 0; r < 4; ++r)
#pragma unroll
            for (int q = 0; q < 4; ++q)
                m[r][q] = mp[r * 4 + q];

        // 4 independent matvec chains; w[k] streamed once, used 4x
        float4 h[4] = { b4, b4, b4, b4 };
#pragma unroll
        for (int k = 0; k < NBINS; ++k) {
            const float4 wk = *reinterpret_cast<const float4*>(&mlp_w[k * D_MODEL + d0]);
#pragma unroll
            for (int r = 0; r < 4; ++r)
                fma4(h[r], compf(m[r][k >> 2], k & 3), wk);
        }

        // LayerNorm stats: 8 independent butterfly chains
        float s[4], ss[4];
#pragma unroll
        for (int r = 0; r < 4; ++r) {
            s[r]  = h[r].x + h[r].y + h[r].z + h[r].w;
            ss[r] = h[r].x * h[r].x + h[r].y * h[r].y
                  + h[r].z * h[r].z + h[r].w * h[r].w;
        }
#pragma unroll
        for (int o = 32; o > 0; o >>= 1) {
#pragma unroll
            for (int r = 0; r < 4; ++r) {
                s[r]  += __shfl_xor(s[r],  o);
                ss[r] += __shfl_xor(ss[r], o);
            }
        }

        // Epilogue: 4 independent chains (loads -> adds -> store)
#pragma unroll
        for (int r = 0; r < 4; ++r) {
            const float mu   = s[r]  * (1.0f / D_MODEL);
            const float var  = ss[r] * (1.0f / D_MODEL) - mu * mu;
            const float rstd = rsqrtf(var + LN_EPS);
            const int   tok  = compi(tokv, r);
            const int   a    = compi(actv, r);
            const int   st   = compi(strv, r);
            const float vfl  = (tok >= 0) ? 1.0f : 0.0f;

            const float4 aw = *reinterpret_cast<const float4*>(&actor_w[a * D_MODEL + d0]);
            const float4 sw = *reinterpret_cast<const float4*>(&street_w[st * D_MODEL + d0]);
            const float4 pw = *reinterpret_cast<const float4*>(&pos_w[(l0 + r) * D_MODEL + d0]);

            float4 o;
            o.x = (fmaxf((h[r].x - mu) * rstd * g4.x + lb4.x, 0.0f) + aw.x + sw.x + pw.x) * vfl;
            o.y = (fmaxf((h[r].y - mu) * rstd * g4.y + lb4.y, 0.0f) + aw.y + sw.y + pw.y) * vfl;
            o.z = (fmaxf((h[r].z - mu) * rstd * g4.z + lb4.z, 0.0f) + aw.z + sw.z + pw.z) * vfl;
            o.w = (fmaxf((h[r].w - mu) * rstd * g4.w + lb4.w, 0.0f) + aw.w + sw.w + pw.w) * vfl;

            *reinterpret_cast<float4*>(&out[((size_t)(c << 2) + r) * D_MODEL + d0]) = o;
        }
    }
}

extern "C" void kernel_launch(void* const* d_in, const int* in_sizes, int n_in,
                              void* d_out, int out_size, void* d_ws, size_t ws_size,
                              hipStream_t stream) {
    const int*   token_ids      = (const int*)  d_in[0];
    const int*   action_actors  = (const int*)  d_in[1];
    const int*   action_streets = (const int*)  d_in[2];
    const float* legal_masks    = (const float*)d_in[3];
    const float* actor_w        = (const float*)d_in[4];
    const float* street_w       = (const float*)d_in[5];
    const float* pos_w          = (const float*)d_in[6];
    const float* mlp_w          = (const float*)d_in[7];
    const float* mlp_b          = (const float*)d_in[8];
    const float* ln_g           = (const float*)d_in[9];
    const float* ln_b           = (const float*)d_in[10];
    float* out = (float*)d_out;

    dim3 grid(2048), block(256);
    hipLaunchKernelGGL(action_embedding_kernel, grid, block, 0, stream,
                       token_ids, action_actors, action_streets, legal_masks,
                       actor_w, street_w, pos_w, mlp_w, mlp_b, ln_g, ln_b, out);
}

// Round 4
// 376.274 us; speedup vs baseline: 1.5983x; 1.5983x over previous
//
#include <hip/hip_runtime.h>

// Problem constants (from reference)
#define BATCH   2048
#define SEQ     160     // input sequence stride
#define LOUT    128     // END - START
#define D_MODEL 256
#define NBINS   16
#define LN_EPS  1e-5f

typedef float f32x4 __attribute__((ext_vector_type(4)));   // native vec for nontemporal store

// Workspace layout (floats)
#define T0_OFF  0                    // 256 combos x 256 d  (includes mlp_b)
#define T1_OFF  65536                // 256 combos x 256 d
#define P_OFF   131072               // 8 (a,st) x 128 l x 256 d
#define WS_FLOATS (P_OFF + 1024 * D_MODEL)   // 393216 floats = 1.5 MB

// ---------------------------------------------------------------------------
// Builder: T0[c][d] = mlp_b[d] + sum_{k<8, bit k of c} mlp_w[k][d]
//          T1[c][d] =            sum_{k<8, bit k of c} mlp_w[8+k][d]
//          P[(a*4+st)*128+l][d] = actor_w[a][d] + street_w[st][d] + pos_w[l][d]
// grid = 1536 blocks (256 + 256 + 1024), block = 256 threads (one per d).
// ---------------------------------------------------------------------------
__global__ __launch_bounds__(256)
void build_tables_kernel(const float* __restrict__ actor_w,
                         const float* __restrict__ street_w,
                         const float* __restrict__ pos_w,
                         const float* __restrict__ mlp_w,
                         const float* __restrict__ mlp_b,
                         float* __restrict__ ws)
{
    const int bid = blockIdx.x;
    const int d   = threadIdx.x;
    if (bid < 256) {
        const int c = bid;
        float s = mlp_b[d];
#pragma unroll
        for (int k = 0; k < 8; ++k)
            s = fmaf((float)((c >> k) & 1), mlp_w[k * D_MODEL + d], s);
        ws[T0_OFF + c * D_MODEL + d] = s;
    } else if (bid < 512) {
        const int c = bid - 256;
        float s = 0.0f;
#pragma unroll
        for (int k = 0; k < 8; ++k)
            s = fmaf((float)((c >> k) & 1), mlp_w[(8 + k) * D_MODEL + d], s);
        ws[T1_OFF + c * D_MODEL + d] = s;
    } else {
        const int i  = bid - 512;          // (a*4+st)*128 + l
        const int a  = i >> 9;
        const int st = (i >> 7) & 3;
        const int l  = i & 127;
        ws[P_OFF + i * D_MODEL + d] =
            actor_w[a * D_MODEL + d] + street_w[st * D_MODEL + d] + pos_w[l * D_MODEL + d];
    }
}

// ---------------------------------------------------------------------------
// Main: one wave per row. Per row: 3 scalar id loads, 16 uniform mask words
// -> two 8-bit codes (SALU), 2 combo-table float4 loads (L2), LN butterfly,
// 1 P-table float4 load (L2), non-temporal float4 store.
// ---------------------------------------------------------------------------
__global__ __launch_bounds__(256)
void action_embedding_kernel(const int*   __restrict__ token_ids,
                             const int*   __restrict__ action_actors,
                             const int*   __restrict__ action_streets,
                             const float* __restrict__ legal_masks,
                             const float* __restrict__ ln_g,
                             const float* __restrict__ ln_b,
                             const float* __restrict__ ws,
                             float*       __restrict__ out)
{
    const int lane = threadIdx.x & 63;
    const int wave = threadIdx.x >> 6;   // 0..3
    const int d0   = lane << 2;          // 0..252

    const float4 g4  = *reinterpret_cast<const float4*>(&ln_g[d0]);
    const float4 lb4 = *reinterpret_cast<const float4*>(&ln_b[d0]);

    const float* T0 = ws + T0_OFF;
    const float* T1 = ws + T1_OFF;
    const float* P  = ws + P_OFF;

    const int total = BATCH * LOUT;          // 262144 rows
    const int wid   = blockIdx.x * 4 + wave;
    const int nw    = gridDim.x * 4;

    for (int idx = wid; idx < total; idx += nw) {
        const int b = idx >> 7;
        const int l = idx & 127;
        const int off = __builtin_amdgcn_readfirstlane(b * SEQ + l);

        // Wave-uniform scalar metadata
        const int tok = token_ids[off];
        const int a   = action_actors[off];
        const int st  = action_streets[off];

        // 16 mask words (0.0f/1.0f) at uniform address -> two 8-bit codes
        const unsigned* mw = reinterpret_cast<const unsigned*>(&legal_masks[(size_t)off * NBINS]);
        unsigned c0 = 0u, c1 = 0u;
#pragma unroll
        for (int k = 0; k < 8; ++k) {
            c0 |= (mw[k]     ? 1u : 0u) << k;
            c1 |= (mw[k + 8] ? 1u : 0u) << k;
        }
        const int i0 = __builtin_amdgcn_readfirstlane((int)c0);
        const int i1 = __builtin_amdgcn_readfirstlane((int)c1);

        // h = T0[c0] + T1[c1]  (bias folded into T0)
        const float4 t0 = *reinterpret_cast<const float4*>(&T0[i0 * D_MODEL + d0]);
        const float4 t1 = *reinterpret_cast<const float4*>(&T1[i1 * D_MODEL + d0]);
        float4 h;
        h.x = t0.x + t1.x;  h.y = t0.y + t1.y;
        h.z = t0.z + t1.z;  h.w = t0.w + t1.w;

        // LayerNorm stats over 256 = 64 lanes x 4
        float s  = h.x + h.y + h.z + h.w;
        float ss = fmaf(h.x, h.x, fmaf(h.y, h.y, fmaf(h.z, h.z, h.w * h.w)));
#pragma unroll
        for (int o = 32; o > 0; o >>= 1) {
            s  += __shfl_xor(s,  o);
            ss += __shfl_xor(ss, o);
        }
        const float mu   = s * (1.0f / D_MODEL);
        const float var  = ss * (1.0f / D_MODEL) - mu * mu;
        const float rstd = rsqrtf(var + LN_EPS);

        // Combined epilogue table row (uniform index)
        const int pidx = __builtin_amdgcn_readfirstlane((((a << 2) | st) << 7) | l);
        const float4 pw = *reinterpret_cast<const float4*>(&P[(size_t)pidx * D_MODEL + d0]);

        const float vfl = (tok >= 0) ? 1.0f : 0.0f;

        f32x4 o;
        o.x = (fmaxf((h.x - mu) * rstd * g4.x + lb4.x, 0.0f) + pw.x) * vfl;
        o.y = (fmaxf((h.y - mu) * rstd * g4.y + lb4.y, 0.0f) + pw.y) * vfl;
        o.z = (fmaxf((h.z - mu) * rstd * g4.z + lb4.z, 0.0f) + pw.z) * vfl;
        o.w = (fmaxf((h.w - mu) * rstd * g4.w + lb4.w, 0.0f) + pw.w) * vfl;

        __builtin_nontemporal_store(o, reinterpret_cast<f32x4*>(&out[(size_t)idx * D_MODEL + d0]));
    }
}

extern "C" void kernel_launch(void* const* d_in, const int* in_sizes, int n_in,
                              void* d_out, int out_size, void* d_ws, size_t ws_size,
                              hipStream_t stream) {
    const int*   token_ids      = (const int*)  d_in[0];
    const int*   action_actors  = (const int*)  d_in[1];
    const int*   action_streets = (const int*)  d_in[2];
    const float* legal_masks    = (const float*)d_in[3];
    const float* actor_w        = (const float*)d_in[4];
    const float* street_w       = (const float*)d_in[5];
    const float* pos_w          = (const float*)d_in[6];
    const float* mlp_w          = (const float*)d_in[7];
    const float* mlp_b          = (const float*)d_in[8];
    const float* ln_g           = (const float*)d_in[9];
    const float* ln_b           = (const float*)d_in[10];
    float* out = (float*)d_out;
    float* ws  = (float*)d_ws;   // needs 1.5 MB

    hipLaunchKernelGGL(build_tables_kernel, dim3(1536), dim3(256), 0, stream,
                       actor_w, street_w, pos_w, mlp_w, mlp_b, ws);

    hipLaunchKernelGGL(action_embedding_kernel, dim3(2048), dim3(256), 0, stream,
                       token_ids, action_actors, action_streets, legal_masks,
                       ln_g, ln_b, ws, out);
}

// Round 6
// 362.164 us; speedup vs baseline: 1.6606x; 1.0390x over previous
//
#include <hip/hip_runtime.h>

// Problem constants (from reference)
#define BATCH   2048
#define SEQ     160     // input sequence stride
#define LOUT    128     // END - START
#define D_MODEL 256
#define NBINS   16
#define LN_EPS  1e-5f

typedef float f32x4 __attribute__((ext_vector_type(4)));

// Workspace layout (floats)
#define T0_OFF  0                        // 256 combos x 256 d (includes mlp_b)
#define T1_OFF  65536                    // 256 combos x 256 d
#define P_OFF   131072                   // 8 (a,st) x 128 l x 256 d
#define MU_OFF  393216                   // 256 x 256 pair means
#define Q_OFF   458752                   // 256 x 256 pair mean-of-squares
#define WS_FLOATS 524288                 // 2 MB total

// ---------------------------------------------------------------------------
// Builder 1: T0[c][d] = mlp_b[d] + sum_{k<8, bit k} mlp_w[k][d]
//            T1[c][d] =            sum_{k<8, bit k} mlp_w[8+k][d]
//            P[(a*4+st)*128+l][d] = actor_w + street_w + pos_w
// ---------------------------------------------------------------------------
__global__ __launch_bounds__(256)
void build_tables_kernel(const float* __restrict__ actor_w,
                         const float* __restrict__ street_w,
                         const float* __restrict__ pos_w,
                         const float* __restrict__ mlp_w,
                         const float* __restrict__ mlp_b,
                         float* __restrict__ ws)
{
    const int bid = blockIdx.x;
    const int d   = threadIdx.x;
    if (bid < 256) {
        const int c = bid;
        float s = mlp_b[d];
#pragma unroll
        for (int k = 0; k < 8; ++k)
            s = fmaf((float)((c >> k) & 1), mlp_w[k * D_MODEL + d], s);
        ws[T0_OFF + c * D_MODEL + d] = s;
    } else if (bid < 512) {
        const int c = bid - 256;
        float s = 0.0f;
#pragma unroll
        for (int k = 0; k < 8; ++k)
            s = fmaf((float)((c >> k) & 1), mlp_w[(8 + k) * D_MODEL + d], s);
        ws[T1_OFF + c * D_MODEL + d] = s;
    } else {
        const int i  = bid - 512;          // (a*4+st)*128 + l
        const int a  = i >> 9;
        const int st = (i >> 7) & 3;
        const int l  = i & 127;
        ws[P_OFF + i * D_MODEL + d] =
            actor_w[a * D_MODEL + d] + street_w[st * D_MODEL + d] + pos_w[l * D_MODEL + d];
    }
}

// ---------------------------------------------------------------------------
// Builder 2: per-pair LN stats. MU[c0,c1] = mean_d(T0[c0]+T1[c1]),
//            Q[c0,c1] = mean_d((T0[c0]+T1[c1])^2).
// grid = 256 (c0), block = 256 (c1). T0 row is wave-uniform (scalar loads).
// ---------------------------------------------------------------------------
__global__ __launch_bounds__(256)
void build_stats_kernel(float* __restrict__ ws)
{
    const int c0 = blockIdx.x;
    const int c1 = threadIdx.x;
    const float* r0 = ws + T0_OFF + c0 * D_MODEL;   // uniform across block
    const float* r1 = ws + T1_OFF + c1 * D_MODEL;   // per-thread row
    float sm = 0.0f, sq = 0.0f;
#pragma unroll 8
    for (int d4 = 0; d4 < D_MODEL / 4; ++d4) {
        const float4 a = *reinterpret_cast<const float4*>(&r0[d4 * 4]);
        const float4 b = *reinterpret_cast<const float4*>(&r1[d4 * 4]);
        const float hx = a.x + b.x, hy = a.y + b.y, hz = a.z + b.z, hw = a.w + b.w;
        sm += hx + hy + hz + hw;
        sq = fmaf(hx, hx, fmaf(hy, hy, fmaf(hz, hz, fmaf(hw, hw, sq))));
    }
    const int idx = (c0 << 8) | c1;
    ws[MU_OFF + idx] = sm * (1.0f / D_MODEL);
    ws[Q_OFF  + idx] = sq * (1.0f / D_MODEL);
}

// ---------------------------------------------------------------------------
// Main: one wave per 2 consecutive rows. Mask bits for BOTH rows come from a
// single __ballot (lanes 0-15 row A, 16-31 row B). LN stats are scalar table
// lookups -> no cross-lane ops, no LDS. 2 independent chains per iteration.
// ---------------------------------------------------------------------------
__global__ __launch_bounds__(256, 6)
void action_embedding_kernel(const int*   __restrict__ token_ids,
                             const int*   __restrict__ action_actors,
                             const int*   __restrict__ action_streets,
                             const float* __restrict__ legal_masks,
                             const float* __restrict__ ln_g,
                             const float* __restrict__ ln_b,
                             const float* __restrict__ ws,
                             float*       __restrict__ out)
{
    const int lane = threadIdx.x & 63;
    const int wave = threadIdx.x >> 6;   // 0..3
    const int d0   = lane << 2;          // 0..252

    const float4 g4  = *reinterpret_cast<const float4*>(&ln_g[d0]);
    const float4 lb4 = *reinterpret_cast<const float4*>(&ln_b[d0]);

    const float* T0 = ws + T0_OFF;
    const float* T1 = ws + T1_OFF;
    const float* P  = ws + P_OFF;
    const float* MU = ws + MU_OFF;
    const float* Q  = ws + Q_OFF;

    // mask-gather lane mapping: rows {A,B}, elements 0..15
    const int mrow = (lane >> 4) & 1;    // lanes 0-15,32-47 -> A; 16-31,48-63 -> B
    const int melt = lane & 15;

    const int npairs = (BATCH * LOUT) / 2;   // 131072
    const int wid    = blockIdx.x * 4 + wave;
    const int nw     = gridDim.x * 4;

    for (int c = wid; c < npairs; c += nw) {
        const int rowA = c * 2;
        const int b    = rowA >> 7;
        const int l0   = rowA & 127;              // even -> rowB same batch row
        const int off  = __builtin_amdgcn_readfirstlane(b * SEQ + l0);

        // --- both rows' mask bits via one ballot ---
        const float mv = legal_masks[(size_t)off * NBINS + mrow * NBINS + melt];
        const unsigned long long bm = __ballot(mv != 0.0f);
        const unsigned lo  = (unsigned)bm;
        const int i0a = lo & 0xFF,          i1a = (lo >> 8)  & 0xFF;
        const int i0b = (lo >> 16) & 0xFF,  i1b = (lo >> 24) & 0xFF;

        // --- wave-uniform scalar metadata for both rows ---
        const int tokA = token_ids[off],      tokB = token_ids[off + 1];
        const int aA   = action_actors[off],  aB   = action_actors[off + 1];
        const int stA  = action_streets[off], stB  = action_streets[off + 1];

        // --- per-pair LN stats (scalar loads, L2-resident 512 KB) ---
        const float muA = MU[(i0a << 8) | i1a];
        const float qA  = Q [(i0a << 8) | i1a];
        const float muB = MU[(i0b << 8) | i1b];
        const float qB  = Q [(i0b << 8) | i1b];
        const float rstdA = rsqrtf(qA - muA * muA + LN_EPS);
        const float rstdB = rsqrtf(qB - muB * muB + LN_EPS);

        // --- vector table rows ---
        const float4 t0a = *reinterpret_cast<const float4*>(&T0[i0a * D_MODEL + d0]);
        const float4 t1a = *reinterpret_cast<const float4*>(&T1[i1a * D_MODEL + d0]);
        const float4 t0b = *reinterpret_cast<const float4*>(&T0[i0b * D_MODEL + d0]);
        const float4 t1b = *reinterpret_cast<const float4*>(&T1[i1b * D_MODEL + d0]);
        const int pidxA = (((aA << 2) | stA) << 7) | l0;
        const int pidxB = (((aB << 2) | stB) << 7) | (l0 + 1);
        const float4 pwa = *reinterpret_cast<const float4*>(&P[(size_t)pidxA * D_MODEL + d0]);
        const float4 pwb = *reinterpret_cast<const float4*>(&P[(size_t)pidxB * D_MODEL + d0]);

        const float vA = (tokA >= 0) ? 1.0f : 0.0f;
        const float vB = (tokB >= 0) ? 1.0f : 0.0f;

        f32x4 oA, oB;
        {
            const float hx = t0a.x + t1a.x, hy = t0a.y + t1a.y,
                        hz = t0a.z + t1a.z, hw = t0a.w + t1a.w;
            oA.x = (fmaxf((hx - muA) * rstdA * g4.x + lb4.x, 0.0f) + pwa.x) * vA;
            oA.y = (fmaxf((hy - muA) * rstdA * g4.y + lb4.y, 0.0f) + pwa.y) * vA;
            oA.z = (fmaxf((hz - muA) * rstdA * g4.z + lb4.z, 0.0f) + pwa.z) * vA;
            oA.w = (fmaxf((hw - muA) * rstdA * g4.w + lb4.w, 0.0f) + pwa.w) * vA;
        }
        {
            const float hx = t0b.x + t1b.x, hy = t0b.y + t1b.y,
                        hz = t0b.z + t1b.z, hw = t0b.w + t1b.w;
            oB.x = (fmaxf((hx - muB) * rstdB * g4.x + lb4.x, 0.0f) + pwb.x) * vB;
            oB.y = (fmaxf((hy - muB) * rstdB * g4.y + lb4.y, 0.0f) + pwb.y) * vB;
            oB.z = (fmaxf((hz - muB) * rstdB * g4.z + lb4.z, 0.0f) + pwb.z) * vB;
            oB.w = (fmaxf((hw - muB) * rstdB * g4.w + lb4.w, 0.0f) + pwb.w) * vB;
        }

        __builtin_nontemporal_store(oA, reinterpret_cast<f32x4*>(&out[(size_t)rowA * D_MODEL + d0]));
        __builtin_nontemporal_store(oB, reinterpret_cast<f32x4*>(&out[((size_t)rowA + 1) * D_MODEL + d0]));
    }
}

extern "C" void kernel_launch(void* const* d_in, const int* in_sizes, int n_in,
                              void* d_out, int out_size, void* d_ws, size_t ws_size,
                              hipStream_t stream) {
    const int*   token_ids      = (const int*)  d_in[0];
    const int*   action_actors  = (const int*)  d_in[1];
    const int*   action_streets = (const int*)  d_in[2];
    const float* legal_masks    = (const float*)d_in[3];
    const float* actor_w        = (const float*)d_in[4];
    const float* street_w       = (const float*)d_in[5];
    const float* pos_w          = (const float*)d_in[6];
    const float* mlp_w          = (const float*)d_in[7];
    const float* mlp_b          = (const float*)d_in[8];
    const float* ln_g           = (const float*)d_in[9];
    const float* ln_b           = (const float*)d_in[10];
    float* out = (float*)d_out;
    float* ws  = (float*)d_ws;   // needs 2 MB

    hipLaunchKernelGGL(build_tables_kernel, dim3(1536), dim3(256), 0, stream,
                       actor_w, street_w, pos_w, mlp_w, mlp_b, ws);
    hipLaunchKernelGGL(build_stats_kernel, dim3(256), dim3(256), 0, stream, ws);
    hipLaunchKernelGGL(action_embedding_kernel, dim3(2048), dim3(256), 0, stream,
                       token_ids, action_actors, action_streets, legal_masks,
                       ln_g, ln_b, ws, out);
}